// Round 3
// baseline (254.516 us; speedup 1.0000x reference)
//
#include <hip/hip_runtime.h>
#include <stdint.h>

typedef unsigned short u16;
typedef unsigned int u32;
typedef short short8 __attribute__((ext_vector_type(8)));
typedef float f32x4 __attribute__((ext_vector_type(4)));
typedef u32 u32x4 __attribute__((ext_vector_type(4)));

#define T_TOT 32768

__device__ __forceinline__ u16 f2bf(float f) {
  u32 u = __float_as_uint(f);
  return (u16)((u + 0x7fffu + ((u >> 16) & 1u)) >> 16);
}
__device__ __forceinline__ float bf2f(u16 h) {
  return __uint_as_float(((u32)h) << 16);
}
__device__ __forceinline__ u32 pk2(float a, float b) {
  return (u32)f2bf(a) | ((u32)f2bf(b) << 16);
}
__device__ __forceinline__ f32x4 max4(f32x4 a, f32x4 b) {
  f32x4 r;
  r[0] = fmaxf(a[0], b[0]); r[1] = fmaxf(a[1], b[1]);
  r[2] = fmaxf(a[2], b[2]); r[3] = fmaxf(a[3], b[3]);
  return r;
}
__device__ __forceinline__ void unp8(uint4 d, float* v) {
  u32 dd[4] = {d.x, d.y, d.z, d.w};
#pragma unroll
  for (int q2 = 0; q2 < 4; ++q2) {
    v[q2 * 2]     = bf2f((u16)(dd[q2] & 0xffffu));
    v[q2 * 2 + 1] = bf2f((u16)(dd[q2] >> 16));
  }
}

// P-redistribution double swap: (a,b) = (word_even, word_odd) of two 16-row
// tiles -> PV A-fragment words. Builtin form lets the compiler insert the
// DPP-class cross-lane wait states (the round-2 inline-asm version lacked
// them and produced stale lane reads).
__device__ __forceinline__ void plswap(u32& a, u32& b) {
#if __has_builtin(__builtin_amdgcn_permlane32_swap) && \
    __has_builtin(__builtin_amdgcn_permlane16_swap)
  typedef u32 u32x2v __attribute__((ext_vector_type(2)));
  u32x2v r = __builtin_amdgcn_permlane32_swap(a, b, false, false);
  u32x2v w = __builtin_amdgcn_permlane16_swap(r[0], r[1], false, false);
  a = w[0]; b = w[1];
#else
  asm volatile(
      "s_nop 2\n\t"
      "v_permlane32_swap_b32 %0, %1\n\t"
      "s_nop 2\n\t"
      "v_permlane16_swap_b32 %0, %1\n\t"
      "s_nop 2"
      : "+v"(a), "+v"(b));
#endif
}

// ---------------------------------------------------------------------------
// Weight convert fp32 -> bf16, row-major [M][K], 16B-chunk XOR swizzle by row.
// ---------------------------------------------------------------------------
__global__ __launch_bounds__(256) void k_wconv(
    const float* __restrict__ fc1, const float* __restrict__ fc2,
    const float* __restrict__ qw, const float* __restrict__ kvw,
    const float* __restrict__ pw, u16* __restrict__ out) {
  int idx = blockIdx.x * 256 + threadIdx.x;  // 32768 chunks total
  const float* src; int K; int rel; u16* dst;
  if (idx < 8192)       { src = fc1; K = 256; rel = idx;         dst = out; }
  else if (idx < 14336) { src = fc2; K = 256; rel = idx - 8192;  dst = out + 65536; }
  else if (idx < 18944) { src = qw;  K = 192; rel = idx - 14336; dst = out + 114688; }
  else if (idx < 28160) { src = kvw; K = 192; rel = idx - 18944; dst = out + 151552; }
  else                  { src = pw;  K = 192; rel = idx - 28160; dst = out + 225280; }
  int nch = K >> 3;
  int m = rel / nch, ch = rel % nch;
  const float* sp = src + (size_t)m * K + ch * 8;
  int pos = (ch & ~7) | ((ch ^ m) & 7);
  u16* dp = dst + (size_t)m * K + pos * 8;
  ushort4 u0, u1;
  u0.x = f2bf(sp[0]); u0.y = f2bf(sp[1]); u0.z = f2bf(sp[2]); u0.w = f2bf(sp[3]);
  u1.x = f2bf(sp[4]); u1.y = f2bf(sp[5]); u1.z = f2bf(sp[6]); u1.w = f2bf(sp[7]);
  *(ushort4*)(dp) = u0;
  *(ushort4*)(dp + 4) = u1;
}

// ---------------------------------------------------------------------------
// Transpose: src fp32 [C][32768] -> dst bf16 [32768][C] token-major swizzled.
// ---------------------------------------------------------------------------
template<int C>
__global__ __launch_bounds__(256) void k_transpose(const float* __restrict__ src,
                                                   u16* __restrict__ dst) {
  __shared__ u16 sT[64][72];
  int c0 = blockIdx.x * 64, t0 = blockIdx.y * 64;
  int tid = threadIdx.x;
  for (int i = tid; i < 1024; i += 256) {
    int row = i >> 4;
    int tb  = (i & 15) * 4;
    const float* sp = src + (size_t)(c0 + row) * T_TOT + t0 + tb;
    float4 v = *(const float4*)sp;
    ushort4 u;
    u.x = f2bf(v.x); u.y = f2bf(v.y); u.z = f2bf(v.z); u.w = f2bf(v.w);
    *(ushort4*)(&sT[row][tb]) = u;
  }
  __syncthreads();
  int tl = tid & 63;
  int jb = tid >> 6;
  for (int p = 0; p < 2; ++p) {
    int j = jb + 4 * p;
    int t = t0 + tl;
    u16 e[8];
#pragma unroll
    for (int e8 = 0; e8 < 8; ++e8) e[e8] = sT[j * 8 + e8][tl];
    int pos = (c0 >> 3) + (j ^ (t & 7));
    uint4 o;
    o.x = (u32)e[0] | ((u32)e[1] << 16);
    o.y = (u32)e[2] | ((u32)e[3] << 16);
    o.z = (u32)e[4] | ((u32)e[5] << 16);
    o.w = (u32)e[6] | ((u32)e[7] << 16);
    *(uint4*)(dst + (size_t)t * C + pos * 8) = o;
  }
}

// ---------------------------------------------------------------------------
// GEMM: out(M x 32768) = W(MxK) * Bt^T. Grid: x = m-tile (adjacent blocks
// share the B t-tile for L2/L3 reuse), y = t-tile.
// ---------------------------------------------------------------------------
enum { EPI_FC1 = 0, EPI_FC2 = 1, EPI_Q = 2, EPI_KV = 3, EPI_PROJ = 4 };

template<int M, int K, int EPI>
__global__ __launch_bounds__(256) void k_gemm(const u16* __restrict__ W,
    const u16* __restrict__ B, const float* __restrict__ bias,
    u16* __restrict__ out, u16* __restrict__ out2) {
  __shared__ u16 lW[64 * 64];
  __shared__ u16 lB[128 * 64];
  int tid = threadIdx.x;
  int lane = tid & 63, wid = tid >> 6;
  int g = lane >> 4, c = lane & 15;
  int wm = wid >> 1, wt = wid & 1;
  int t0 = blockIdx.y * 128, m0 = blockIdx.x * 64;
  f32x4 acc[2][4];
#pragma unroll
  for (int i = 0; i < 2; ++i)
#pragma unroll
    for (int j = 0; j < 4; ++j) acc[i][j] = f32x4{0.f, 0.f, 0.f, 0.f};

  for (int s = 0; s < K / 64; ++s) {
    __syncthreads();
    for (int i = tid; i < 512; i += 256) {
      int r = i >> 3, ch = i & 7;
      *(uint4*)(lW + r * 64 + ch * 8) =
          *(const uint4*)(W + (size_t)(m0 + r) * K + s * 64 + ch * 8);
    }
    for (int i = tid; i < 1024; i += 256) {
      int r = i >> 3, ch = i & 7;
      *(uint4*)(lB + r * 64 + ch * 8) =
          *(const uint4*)(B + (size_t)(t0 + r) * K + s * 64 + ch * 8);
    }
    __syncthreads();
#pragma unroll
    for (int kc = 0; kc < 2; ++kc) {
      short8 af[2], bfr[4];
#pragma unroll
      for (int mt = 0; mt < 2; ++mt) {
        int r = wm * 32 + mt * 16 + c;
        af[mt] = *(const short8*)(lW + r * 64 + (((kc * 4 + g) ^ (r & 7)) << 3));
      }
#pragma unroll
      for (int tt = 0; tt < 4; ++tt) {
        int r = wt * 64 + tt * 16 + c;
        bfr[tt] = *(const short8*)(lB + r * 64 + (((kc * 4 + g) ^ (r & 7)) << 3));
      }
#pragma unroll
      for (int mt = 0; mt < 2; ++mt)
#pragma unroll
        for (int tt = 0; tt < 4; ++tt)
          acc[mt][tt] = __builtin_amdgcn_mfma_f32_16x16x32_bf16(
              af[mt], bfr[tt], acc[mt][tt], 0, 0, 0);
    }
  }

#pragma unroll
  for (int mt = 0; mt < 2; ++mt) {
    int m_base = m0 + wm * 32 + mt * 16 + 4 * g;
    float br[4];
    if constexpr (EPI == EPI_KV) {
      if (m_base < 192) { br[0] = br[1] = br[2] = br[3] = 0.f; }
      else {
        float4 b4 = *(const float4*)(bias + (m_base - 192));
        br[0] = b4.x; br[1] = b4.y; br[2] = b4.z; br[3] = b4.w;
      }
    } else {
      float4 b4 = *(const float4*)(bias + m_base);
      br[0] = b4.x; br[1] = b4.y; br[2] = b4.z; br[3] = b4.w;
    }
#pragma unroll
    for (int tt = 0; tt < 4; ++tt) {
      int t = t0 + wt * 64 + tt * 16 + c;
      float v[4];
#pragma unroll
      for (int r = 0; r < 4; ++r) v[r] = acc[mt][tt][r] + br[r];
      if constexpr (EPI == EPI_FC1) {
#pragma unroll
        for (int r = 0; r < 4; ++r)
          v[r] = 0.5f * v[r] * (1.0f + erff(v[r] * 0.70710678118654752f));
      }
      if constexpr (EPI == EPI_FC1 || EPI == EPI_FC2) {
        ushort4 u;
        u.x = f2bf(v[0]); u.y = f2bf(v[1]); u.z = f2bf(v[2]); u.w = f2bf(v[3]);
        int pos = (m_base >> 3) ^ (t & 7);
        *(ushort4*)(out + (size_t)t * M + (pos << 3) + (m_base & 7)) = u;
      } else if constexpr (EPI == EPI_PROJ) {
        ushort4 u;
        u.x = f2bf(v[0]); u.y = f2bf(v[1]); u.z = f2bf(v[2]); u.w = f2bf(v[3]);
        *(ushort4*)(out + (size_t)t * 192 + m_base) = u;
      } else {
        int z = t >> 10, y = (t >> 5) & 31, xx = t & 31;
        int win = ((z >> 3) << 4) + ((y >> 3) << 2) + (xx >> 3);
        int n = ((z & 7) << 6) + ((y & 7) << 3) + (xx & 7);
        if (EPI == EPI_Q || m_base < 192) {
          int head = m_base >> 5, dim = m_base & 31;
          ushort4 u;
          u.x = f2bf(v[0]); u.y = f2bf(v[1]); u.z = f2bf(v[2]); u.w = f2bf(v[3]);
          *(ushort4*)(out + ((size_t)(win * 6 + head) * 512 + n) * 32 + dim) = u;
        } else {
          int vb = m_base - 192;
          int head = vb >> 5, dimb = vb & 31;
#pragma unroll
          for (int r = 0; r < 4; ++r) {
            int dimr = dimb + r;
            out2[((size_t)(win * 6 + head) * 32 + dimr) * 512 +
                 (((n >> 3) ^ (dimr & 7)) << 3) + (n & 7)] = f2bf(v[r]);
          }
        }
      }
    }
  }
}

// ---------------------------------------------------------------------------
// Row-normalize Q (folding exp(min(ls,ln100))*log2e) and K, in place.
// ---------------------------------------------------------------------------
__global__ __launch_bounds__(256) void k_qknorm(u16* __restrict__ Qw,
    u16* __restrict__ Kw, const float* __restrict__ ls) {
  int idx = blockIdx.x * 256 + threadIdx.x;
  bool isQ = idx < 196608;
  u16* p = isQ ? (Qw + (size_t)idx * 32) : (Kw + (size_t)(idx - 196608) * 32);
  uint4 d0 = *(const uint4*)(p);
  uint4 d1 = *(const uint4*)(p + 8);
  uint4 d2 = *(const uint4*)(p + 16);
  uint4 d3 = *(const uint4*)(p + 24);
  float v[32];
  unp8(d0, v); unp8(d1, v + 8); unp8(d2, v + 16); unp8(d3, v + 24);
  float ss = 0.f;
#pragma unroll
  for (int i = 0; i < 32; ++i) ss += v[i] * v[i];
  float rn = 1.0f / fmaxf(sqrtf(ss), 1e-12f);
  if (isQ) {
    int head = (idx >> 9) % 6;
    rn *= __expf(fminf(ls[head], 4.6051701859880914f)) * 1.4426950408889634f;
  }
  uint4 o0, o1, o2, o3;
  o0.x = pk2(v[0] * rn, v[1] * rn);   o0.y = pk2(v[2] * rn, v[3] * rn);
  o0.z = pk2(v[4] * rn, v[5] * rn);   o0.w = pk2(v[6] * rn, v[7] * rn);
  o1.x = pk2(v[8] * rn, v[9] * rn);   o1.y = pk2(v[10] * rn, v[11] * rn);
  o1.z = pk2(v[12] * rn, v[13] * rn); o1.w = pk2(v[14] * rn, v[15] * rn);
  o2.x = pk2(v[16] * rn, v[17] * rn); o2.y = pk2(v[18] * rn, v[19] * rn);
  o2.z = pk2(v[20] * rn, v[21] * rn); o2.w = pk2(v[22] * rn, v[23] * rn);
  o3.x = pk2(v[24] * rn, v[25] * rn); o3.y = pk2(v[26] * rn, v[27] * rn);
  o3.z = pk2(v[28] * rn, v[29] * rn); o3.w = pk2(v[30] * rn, v[31] * rn);
  *(uint4*)(p) = o0;
  *(uint4*)(p + 8) = o1;
  *(uint4*)(p + 16) = o2;
  *(uint4*)(p + 24) = o3;
}

// ---------------------------------------------------------------------------
// Windowed cosine attention. Grid (zq=4, win=64, head=6), 256 thr = 4 waves,
// each wave does 2 q-tiles of 16 rows. Softmax base-2, all-register P
// redistribution via permlane32/16 swap builtins.
// ---------------------------------------------------------------------------
__global__ __launch_bounds__(256) void k_attn(const u16* __restrict__ Qw,
    const u16* __restrict__ Kw, const u16* __restrict__ Vw,
    u16* __restrict__ Amat) {
  extern __shared__ char smem[];
  u16* Kn = (u16*)smem;              // [512][36] padded rows (72B stride)
  u16* Vt = (u16*)(smem + 36864);    // [32][512] dim-major, chunk-swizzled
  int tid = threadIdx.x, lane = tid & 63, wid = tid >> 6;
  int g = lane >> 4, c = lane & 15;
  int zq = blockIdx.x, win = blockIdx.y, head = blockIdx.z;
  const u16* Kg = Kw + (size_t)(win * 6 + head) * 16384;
  const u16* Vg = Vw + (size_t)(win * 6 + head) * 16384;
  const u16* Qg = Qw + (size_t)(win * 6 + head) * 16384;
  for (int i = tid; i < 2048; i += 256) {
    int r = i >> 2, ch = i & 3;
    *(uint4*)(Kn + r * 36 + ch * 8) = *(const uint4*)(Kg + (size_t)i * 8);
  }
  for (int i = tid; i < 2048; i += 256)
    *(uint4*)(Vt + i * 8) = *(const uint4*)(Vg + (size_t)i * 8);
  __syncthreads();

  int wz = win >> 4, wy = (win >> 2) & 3, wx = win & 3;

  for (int qi = 0; qi < 2; ++qi) {
    int q0 = zq * 128 + wid * 32 + qi * 16;
    short8 qf = *(const short8*)(Qg + (size_t)(q0 + c) * 32 + g * 8);

    // S^T = mfma(K, Q): lane (g,c) holds S[n'=tt*16+4g+r][q=c]
    f32x4 s[32];
#pragma unroll
    for (int tt = 0; tt < 32; ++tt) {
      short8 kf = *(const short8*)(Kn + (size_t)(tt * 16 + c) * 36 + g * 8);
      s[tt] = __builtin_amdgcn_mfma_f32_16x16x32_bf16(
          kf, qf, f32x4{0.f, 0.f, 0.f, 0.f}, 0, 0, 0);
    }
    // max tree (log depth)
    f32x4 t8[8];
#pragma unroll
    for (int i = 0; i < 8; ++i)
      t8[i] = max4(max4(s[i], s[i + 8]), max4(s[i + 16], s[i + 24]));
#pragma unroll
    for (int i = 0; i < 4; ++i) t8[i] = max4(t8[i], t8[i + 4]);
    t8[0] = max4(max4(t8[0], t8[1]), max4(t8[2], t8[3]));
    float mx = fmaxf(fmaxf(t8[0][0], t8[0][1]), fmaxf(t8[0][2], t8[0][3]));
    mx = fmaxf(mx, __shfl_xor(mx, 16));
    mx = fmaxf(mx, __shfl_xor(mx, 32));

    // exp2, pack to bf16 pairs, sum
    u32 pk[64];
    f32x4 sum4 = {0.f, 0.f, 0.f, 0.f};
#pragma unroll
    for (int tt = 0; tt < 32; ++tt) {
      f32x4 p;
#pragma unroll
      for (int r = 0; r < 4; ++r) p[r] = __builtin_amdgcn_exp2f(s[tt][r] - mx);
      sum4 += p;
      pk[tt * 2]     = pk2(p[0], p[1]);
      pk[tt * 2 + 1] = pk2(p[2], p[3]);
    }
    float sum = (sum4[0] + sum4[1]) + (sum4[2] + sum4[3]);
    sum += __shfl_xor(sum, 16);
    sum += __shfl_xor(sum, 32);
    float rs = 1.0f / sum;

    // PV with in-register P redistribution.
    f32x4 o0 = {0.f, 0.f, 0.f, 0.f}, o1 = {0.f, 0.f, 0.f, 0.f};
#pragma unroll
    for (int kc = 0; kc < 16; ++kc) {
      u32 wa = pk[kc * 4 + 0], wc = pk[kc * 4 + 2];
      plswap(wa, wc);
      u32 wb = pk[kc * 4 + 1], wd = pk[kc * 4 + 3];
      plswap(wb, wd);
      u32x4 pw;
      pw[0] = wa; pw[1] = wb; pw[2] = wc; pw[3] = wd;
      short8 pf = __builtin_bit_cast(short8, pw);
      int chpos = ((kc * 4 + g) ^ (c & 7)) << 3;
      short8 vf0 = *(const short8*)(Vt + (size_t)c * 512 + chpos);
      o0 = __builtin_amdgcn_mfma_f32_16x16x32_bf16(pf, vf0, o0, 0, 0, 0);
      short8 vf1 = *(const short8*)(Vt + (size_t)(16 + c) * 512 + chpos);
      o1 = __builtin_amdgcn_mfma_f32_16x16x32_bf16(pf, vf1, o1, 0, 0, 0);
    }

    // epilogue: fold 1/sum (per q-row) into O, scatter to Amat
    float rs4[4];
#pragma unroll
    for (int r = 0; r < 4; ++r)
      rs4[r] = __shfl(rs, (lane & 48) | (((lane >> 4) & 3) * 4 + r));
    int cg0 = head * 32 + c;
    int cg1 = cg0 + 16;
#pragma unroll
    for (int r = 0; r < 4; ++r) {
      int n = q0 + 4 * g + r;
      int dz = n >> 6, dy = (n >> 3) & 7, dx = n & 7;
      int t = (wz * 8 + dz) * 1024 + (wy * 8 + dy) * 32 + wx * 8 + dx;
      Amat[(size_t)t * 192 + (((cg0 >> 3) ^ (t & 7)) << 3) + (cg0 & 7)] =
          f2bf(o0[r] * rs4[r]);
      Amat[(size_t)t * 192 + (((cg1 >> 3) ^ (t & 7)) << 3) + (cg1 & 7)] =
          f2bf(o1[r] * rs4[r]);
    }
  }
}

// ---------------------------------------------------------------------------
// Residual + LayerNorm: out[c][t] = x[c][t] + LN(O2[t][:])*g + b
// ---------------------------------------------------------------------------
__global__ __launch_bounds__(256) void k_ln(const u16* __restrict__ O2,
    const float* __restrict__ x, const float* __restrict__ gg,
    const float* __restrict__ bb, float* __restrict__ out) {
  __shared__ float sO[64][201];
  __shared__ float sm_[64], sr_[64];
  int tid = threadIdx.x;
  int t0 = blockIdx.x * 64;
  for (int i = tid; i < 1536; i += 256) {
    int row = i / 24, c16 = i % 24;
    uint4 d = *(const uint4*)(O2 + (size_t)(t0 + row) * 192 + c16 * 8);
    u32 dd[4] = {d.x, d.y, d.z, d.w};
#pragma unroll
    for (int q2 = 0; q2 < 4; ++q2) {
      sO[row][c16 * 8 + q2 * 2]     = bf2f((u16)(dd[q2] & 0xffffu));
      sO[row][c16 * 8 + q2 * 2 + 1] = bf2f((u16)(dd[q2] >> 16));
    }
  }
  __syncthreads();
  int tk = tid >> 2, part = tid & 3;
  float s1 = 0.f, s2 = 0.f;
  for (int i = 0; i < 48; ++i) {
    float v = sO[tk][part * 48 + i];
    s1 += v;
    s2 += v * v;
  }
  s1 += __shfl_xor(s1, 1); s1 += __shfl_xor(s1, 2);
  s2 += __shfl_xor(s2, 1); s2 += __shfl_xor(s2, 2);
  float mean = s1 * (1.0f / 192.0f);
  float var = s2 * (1.0f / 192.0f) - mean * mean;
  float rstd = rsqrtf(var + 1e-5f);
  if (part == 0) { sm_[tk] = mean; sr_[tk] = rstd; }
  __syncthreads();
  for (int i = tid; i < 12288; i += 256) {
    int cc = i >> 6, tl = i & 63;
    size_t gi = (size_t)cc * T_TOT + t0 + tl;
    out[gi] = x[gi] + (sO[tl][cc] - sm_[tl]) * sr_[tl] * gg[cc] + bb[cc];
  }
}

// ---------------------------------------------------------------------------
extern "C" void kernel_launch(void* const* d_in, const int* in_sizes, int n_in,
                              void* d_out, int out_size, void* d_ws, size_t ws_size,
                              hipStream_t stream) {
  const float* x      = (const float*)d_in[0];
  const float* prev   = (const float*)d_in[1];
  const float* fc1_w  = (const float*)d_in[2];
  const float* fc1_b  = (const float*)d_in[3];
  const float* fc2_w  = (const float*)d_in[4];
  const float* fc2_b  = (const float*)d_in[5];
  const float* q_w    = (const float*)d_in[6];
  const float* q_b    = (const float*)d_in[7];
  const float* kv_w   = (const float*)d_in[8];
  const float* v_b    = (const float*)d_in[9];
  const float* proj_w = (const float*)d_in[10];
  const float* proj_b = (const float*)d_in[11];
  const float* lsc    = (const float*)d_in[12];
  const float* ln_g   = (const float*)d_in[13];
  const float* ln_b   = (const float*)d_in[14];
  float* out = (float*)d_out;
  char* ws = (char*)d_ws;

  u16* Pt   = (u16*)(ws + 0);          // [32768][256] bf16 swz   (16 MiB)
  u16* Y1t  = (u16*)(ws + 16777216);   // [32768][256]            (16 MiB)
  u16* Zt   = (u16*)(ws + 33554432);   // [32768][192]            (12 MiB)
  u16* Xt   = (u16*)(ws + 46137344);   // [32768][192]            (12 MiB)
  u16* Kwin = (u16*)(ws + 58720256);   // [64][6][512][32]        (12 MiB)
  u16* Vwin = (u16*)(ws + 71303168);   // [64][6][32][512] swz    (12 MiB)
  u16* Wbf  = (u16*)(ws + 83886080);   // 262144 bf16 weights
  u16* Qwin = Pt;    // alias: Pt dead after fc1
  u16* Amat = Y1t;   // alias: Y1t dead after fc2
  u16* O2t  = Xt;    // alias: Xt dead after q-GEMM

  k_wconv<<<128, 256, 0, stream>>>(fc1_w, fc2_w, q_w, kv_w, proj_w, Wbf);
  k_transpose<256><<<dim3(4, 512), 256, 0, stream>>>(prev, Pt);
  k_transpose<192><<<dim3(3, 512), 256, 0, stream>>>(x, Xt);
  k_gemm<256, 256, EPI_FC1><<<dim3(4, 256), 256, 0, stream>>>(Wbf, Pt, fc1_b, Y1t, nullptr);
  k_gemm<192, 256, EPI_FC2><<<dim3(3, 256), 256, 0, stream>>>(Wbf + 65536, Y1t, fc2_b, Zt, nullptr);
  k_gemm<192, 192, EPI_Q><<<dim3(3, 256), 256, 0, stream>>>(Wbf + 114688, Xt, q_b, Qwin, nullptr);
  k_gemm<384, 192, EPI_KV><<<dim3(6, 256), 256, 0, stream>>>(Wbf + 151552, Zt, v_b, Kwin, Vwin);
  k_qknorm<<<1536, 256, 0, stream>>>(Qwin, Kwin, lsc);
  k_attn<<<dim3(4, 64, 6), 256, 69632, stream>>>(Qwin, Kwin, Vwin, Amat);
  k_gemm<192, 192, EPI_PROJ><<<dim3(3, 256), 256, 0, stream>>>(Wbf + 225280, Amat, proj_b, O2t, nullptr);
  k_ln<<<512, 256, 0, stream>>>(O2t, x, ln_g, ln_b, out);
}